// Round 5
// baseline (136.058 us; speedup 1.0000x reference)
//
#include <hip/hip_runtime.h>
#include <stdint.h>

// Problem constants (fixed shapes from reference)
#define M_ROWS 6272   // 32*196
#define K_DIM  768
#define N_DIM  3072
#define BM 128
#define BN 256
#define BK 32
#define NITER (K_DIM / BK)   // 24

#define X_CHUNKS (M_ROWS * K_DIM / 8)   // 602112
#define W_CHUNKS (N_DIM * K_DIM / 8)    // 294912
#define X_BLOCKS (X_CHUNKS / 256)       // 2352
#define W_BLOCKS (W_CHUNKS / 256)       // 1152

#define GRID_X (N_DIM / BN)             // 12
#define GRID_Y (M_ROWS / BM)            // 49
#define NWG    (GRID_X * GRID_Y)        // 588

typedef unsigned short u16;
typedef __attribute__((ext_vector_type(8))) __bf16 bf16x8;
typedef __attribute__((ext_vector_type(4))) float f32x4;

__device__ __forceinline__ u16 f32_to_bf16(float f) {
    unsigned u = __float_as_uint(f);
    unsigned r = 0x7FFFu + ((u >> 16) & 1u);
    return (u16)((u + r) >> 16);
}

__device__ __forceinline__ unsigned pack2(float a, float b) {
    return (unsigned)f32_to_bf16(a) | ((unsigned)f32_to_bf16(b) << 16);
}

// Async global->LDS DMA, 16B per lane. LDS dest is wave-uniform base +
// lane*16 (hardware rule); global source is per-lane.
#define GLOAD16(gp, lp) __builtin_amdgcn_global_load_lds( \
    (const __attribute__((address_space(1))) void*)(gp),  \
    (__attribute__((address_space(3))) void*)(lp), 16, 0, 0)

// Fused prep (verified): blocks [0, X_BLOCKS) cast x fp32->bf16;
// blocks [X_BLOCKS, X_BLOCKS+W_BLOCKS) expand block-circulant W to bf16.
__global__ void prep_kernel(const float* __restrict__ x, const float* __restrict__ w,
                            u16* __restrict__ xb, u16* __restrict__ wb) {
    int b = blockIdx.x;
    if (b < X_BLOCKS) {
        int idx = b * 256 + threadIdx.x;
        const float4* xp = (const float4*)x + (size_t)idx * 2;
        float4 a = xp[0], c = xp[1];
        uint4 v;
        v.x = pack2(a.x, a.y);
        v.y = pack2(a.z, a.w);
        v.z = pack2(c.x, c.y);
        v.w = pack2(c.z, c.w);
        ((uint4*)xb)[idx] = v;
    } else {
        int idx = (b - X_BLOCKS) * 256 + threadIdx.x;
        int n    = idx / 96;          // output row [0,3072)
        int kc   = idx - n * 96;      // 8-elem chunk along K
        int kblk = n / 768;           // 0..3
        int o    = n - kblk * 768;    // 0..767
        int j    = kc / 24;           // 0..3
        int c8   = kc - j * 24;       // 0..23
        int i    = (kblk - j) & 3;    // (kblk - j) mod 4
        const float* src = w + (((size_t)i * 768 + o) * 192 + c8 * 8);
        float4 a = ((const float4*)src)[0];
        float4 c = ((const float4*)src)[1];
        uint4 v;
        v.x = pack2(a.x, a.y);
        v.y = pack2(a.z, a.w);
        v.z = pack2(c.x, c.y);
        v.w = pack2(c.z, c.w);
        ((uint4*)wb)[idx] = v;
    }
}

// C[m,n] = sum_k A[m,k]*B[n,k] + bias[n]; A,B bf16 row-major K-contig, C fp32.
//
// Round-5 change: WAVE-TILE RESHAPE (the LDS-bytes-per-MFMA lever).
// 4 waves/block (256 thr), each wave owns a 128x64 output tile: acc[8][4],
// 32 MFMA per K-step against 12 ds_read_b128 -> amortized ds_read traffic
// drops 512 -> 384 B per MFMA (-25%). All four prior schedules plateaued at
// ~51us with identical 4x4 reuse; MfmaUtil 21% matches the LDS-read-BW cap
// for 512 B/MFMA, so reuse geometry -- not the schedule -- is the lever.
//
// Skeleton otherwise = verified round-3: triple-buffered global_load_lds
// (one K-tile per buffer; while computing kt from buf kt%3, tile kt+1 sits
// landed, tile kt+2's 6 DMA issues/thread target the buffer freed at kt-1's
// barrier), counted s_waitcnt vmcnt(6) before the lgkm-only barrier (never
// 0 in the main loop), XOR swizzle (conflicts=0 verified), m204 XCD swizzle.
__global__ __launch_bounds__(256, 2) void gemm_bt(
    const u16* __restrict__ A,    // [M_ROWS, K_DIM] bf16
    const u16* __restrict__ B,    // [N_DIM,  K_DIM] bf16
    const float* __restrict__ bias,
    float* __restrict__ C)
{
    __shared__ __align__(16) u16 As[3][BM * BK];   // 3 x 8 KB
    __shared__ __align__(16) u16 Bs[3][BN * BK];   // 3 x 16 KB  (72 KB total)

    // ---- XCD-aware bijective remap of the 1-D block id ----
    const int orig = blockIdx.x;
    const int xcd  = orig & 7;
    const int pos  = orig >> 3;
    const int q    = NWG >> 3;          // 73
    const int r    = NWG & 7;           // 4
    const int lin  = (xcd < r ? xcd * (q + 1) : r * (q + 1) + (xcd - r) * q) + pos;
    const int rowBlk = lin / GRID_X;    // 0..48
    const int colBlk = lin - rowBlk * GRID_X;

    const int rowBase = rowBlk * BM;
    const int colBase = colBlk * BN;

    const int tid    = threadIdx.x;
    const int wave   = tid >> 6;    // 0..3 -> 64-col slice each
    const int lane   = tid & 63;
    const int lane16 = lane & 15;
    const int quad   = lane >> 4;
    const int wc     = wave;        // wave col (0..3)

    // DMA source addressing. Chunk c: row = c>>2, lds slot = c&3, global
    // k-slot = (c&3)^((row>>1)&3). Thread t owns chunks {t, t+256, ...}:
    // rows 64 apart, same (c&3) and same row-parity class mod 4
    // ((r+64)>>1 & 3 == r>>1 & 3), so ONE swizzled base + row-stride serves
    // all of a thread's chunks.
    const int rA = tid >> 2;
    const int sA = (tid & 3) ^ ((rA >> 1) & 3);

    const uint4* Ag = (const uint4*)(A + (size_t)(rowBase + rA) * K_DIM + sA * 8);
    const uint4* Bg = (const uint4*)(B + (size_t)(colBase + rA) * K_DIM + sA * 8);
    const int rowStride = 64 * (K_DIM / 8);   // 6144 uint4 per 64 rows

    // DMA dest: wave-uniform base; HW adds lane*16. Chunk c = wave*64+lane
    // (+256k) lands at byte c*16 = wave*1024 + lane*16 + k*4096.
    char* AsB = (char*)As + wave * 1024;
    char* BsB = (char*)Bs + wave * 1024;

#define ISSUE(g, b) do {                                                    \
        GLOAD16(Ag + (g) * 4,                 AsB + (b) * 8192);            \
        GLOAD16(Ag + (g) * 4 + rowStride,     AsB + (b) * 8192 + 4096);     \
        GLOAD16(Bg + (g) * 4,                 BsB + (b) * 16384);           \
        GLOAD16(Bg + (g) * 4 + rowStride,     BsB + (b) * 16384 + 4096);    \
        GLOAD16(Bg + (g) * 4 + 2 * rowStride, BsB + (b) * 16384 + 8192);    \
        GLOAD16(Bg + (g) * 4 + 3 * rowStride, BsB + (b) * 16384 + 12288);   \
    } while (0)

    // read-side swizzle (same scheme, verified conflicts=0):
    // row = i*16+lane16 -> (row>>1)&3 == (lane16>>1)&3 (i*8 ≡ 0 mod 4)
    const int swz  = (lane16 >> 1) & 3;
    const int slot = (quad ^ swz) * 8;
    int aoff[8], boff[4];
#pragma unroll
    for (int i = 0; i < 8; ++i)
        aoff[i] = (i * 16 + lane16) * BK + slot;
#pragma unroll
    for (int j = 0; j < 4; ++j)
        boff[j] = (wc * 64 + j * 16 + lane16) * BK + slot;

    f32x4 acc[8][4] = {};

#define DS_READS(cb)                                                        \
    _Pragma("unroll") for (int i = 0; i < 8; ++i)                           \
        af[i] = *(const bf16x8*)&As[cb][aoff[i]];                           \
    _Pragma("unroll") for (int j = 0; j < 4; ++j)                           \
        bfv[j] = *(const bf16x8*)&Bs[cb][boff[j]];

#define MFMA32()                                                            \
    __builtin_amdgcn_s_setprio(1);                                          \
    _Pragma("unroll") for (int i = 0; i < 8; ++i)                           \
    _Pragma("unroll") for (int j = 0; j < 4; ++j)                           \
        acc[i][j] = __builtin_amdgcn_mfma_f32_16x16x32_bf16(                \
            af[i], bfv[j], acc[i][j], 0, 0, 0);                             \
    __builtin_amdgcn_s_setprio(0);

    // steady state: read kt (landed at kt-1's vmcnt+barrier), issue kt+2
    // (its buffer's reads drained at kt-1's barrier), vmcnt(6) lands kt+1
    // (kt+2's 6 stay in flight), lgkm-only barrier, MFMA.
#define ITER_ISSUE(cb, fb, g) {                                             \
        bf16x8 af[8], bfv[4];                                               \
        DS_READS(cb)                                                        \
        ISSUE(g, fb);                                                       \
        asm volatile("s_waitcnt vmcnt(6)" ::: "memory");                    \
        asm volatile("s_waitcnt lgkmcnt(0)\n\ts_barrier" ::: "memory");     \
        MFMA32()                                                            \
    }

#define ITER_DRAIN(cb) {                                                    \
        bf16x8 af[8], bfv[4];                                               \
        DS_READS(cb)                                                        \
        asm volatile("s_waitcnt vmcnt(0)" ::: "memory");                    \
        asm volatile("s_waitcnt lgkmcnt(0)\n\ts_barrier" ::: "memory");     \
        MFMA32()                                                            \
    }

#define ITER_FINAL(cb) {                                                    \
        bf16x8 af[8], bfv[4];                                               \
        DS_READS(cb)                                                        \
        MFMA32()                                                            \
    }

    // prologue: tiles 0 and 1 fully in flight; land tile 0 (tile 1 rides)
    ISSUE(0, 0);
    ISSUE(1, 1);
    asm volatile("s_waitcnt vmcnt(6)\n\ts_barrier" ::: "memory");

    // kt = 0..20 (buffer pattern repeats mod 3), each issues kt+2
    for (int t = 0; t < 7; ++t) {
        const int g = t * 3;
        ITER_ISSUE(0, 2, g + 2);
        ITER_ISSUE(1, 0, g + 3);
        ITER_ISSUE(2, 1, g + 4);
    }
    ITER_ISSUE(0, 2, 23);   // kt=21: issues last tile (23)
    ITER_DRAIN(1);          // kt=22: land tile 23
    ITER_FINAL(2);          // kt=23: compute only

    // epilogue: C[row][col] = acc + bias[col]
    float bv[4];
#pragma unroll
    for (int j = 0; j < 4; ++j)
        bv[j] = bias[colBase + wc * 64 + j * 16 + lane16];
#pragma unroll
    for (int i = 0; i < 8; ++i) {
        int row0 = rowBase + i * 16 + quad * 4;
#pragma unroll
        for (int r2 = 0; r2 < 4; ++r2) {
            float* cp = C + (size_t)(row0 + r2) * N_DIM + colBase + wc * 64 + lane16;
#pragma unroll
            for (int j = 0; j < 4; ++j)
                cp[j * 16] = acc[i][j][r2] + bv[j];
        }
    }
#undef ISSUE
#undef DS_READS
#undef MFMA32
#undef ITER_ISSUE
#undef ITER_DRAIN
#undef ITER_FINAL
}

extern "C" void kernel_launch(void* const* d_in, const int* in_sizes, int n_in,
                              void* d_out, int out_size, void* d_ws, size_t ws_size,
                              hipStream_t stream) {
    const float* x    = (const float*)d_in[0];
    const float* w    = (const float*)d_in[1];
    const float* bias = (const float*)d_in[2];
    float* out = (float*)d_out;

    u16* xb = (u16*)d_ws;                                       // 9,633,792 B
    u16* wb = (u16*)((char*)d_ws + (size_t)M_ROWS * K_DIM * 2); // +4,718,592 B

    hipLaunchKernelGGL(prep_kernel, dim3(X_BLOCKS + W_BLOCKS), dim3(256),
                       0, stream, x, w, xb, wb);
    hipLaunchKernelGGL(gemm_bt, dim3(NWG), dim3(256),
                       0, stream, xb, wb, bias, out);
}